// Round 11
// baseline (262.866 us; speedup 1.0000x reference)
//
#include <hip/hip_runtime.h>
#include <hip/hip_fp16.h>

#define N_NODES 50000
#define N_EDGES 800000

typedef short  bf16x8 __attribute__((ext_vector_type(8)));
typedef float  f32x4  __attribute__((ext_vector_type(4)));
typedef _Float16 h16x2 __attribute__((ext_vector_type(2)));

// 32-bit fixed point, scale 2^22; VALIDATED rounds 8/9.
// NEW (v11): two adjacent columns ride one u64 atomic. Addend =
// ((u64)(u32)iv_hi << 32) + sext64(iv_lo). u64 addition is associative+
// commutative mod 2^64 => bitwise-deterministic. Decode is EXACT because
// each field's node-sum fits int32 (|sum| <= 5.7e8 < 2^31, 3.7x margin):
//   lo = (int)low32(S); hi = (int)high32(S) + (low32(S) >> 31)  [borrow fix]
#define FXP32_SCALE 4194304.0f                 // 2^22
#define FXP32_INV   2.384185791015625e-07f     // 2^-22

#define WSB_BYTES   (36864 * 2)                // 73,728 B

__device__ __forceinline__ unsigned short f2bf(float f) {
    unsigned u = __float_as_uint(f);
    u += 0x7FFF + ((u >> 16) & 1);          // RNE
    return (unsigned short)(u >> 16);
}

__device__ __forceinline__ f32x4 fma4(f32x4 a, f32x4 b, f32x4 c) {
    f32x4 r;
    r[0] = fmaf(a[0], b[0], c[0]);
    r[1] = fmaf(a[1], b[1], c[1]);
    r[2] = fmaf(a[2], b[2], c[2]);
    r[3] = fmaf(a[3], b[3], c[3]);
    return r;
}

#if __has_builtin(__builtin_amdgcn_fdot2)
__device__ __forceinline__ float FDOT2(h16x2 a, h16x2 b, float c) {
    return __builtin_amdgcn_fdot2(a, b, c, false);
}
#else
__device__ __forceinline__ float FDOT2(h16x2 a, h16x2 b, float c) {
    return fmaf((float)a.x, (float)b.x, fmaf((float)a.y, (float)b.y, c));
}
#endif

// pack a column-pair contribution into one u64 atomic addend
__device__ __forceinline__ unsigned long long pack_pair(float v0, float v1, float sc) {
    int i0 = __float2int_rn(v0 * sc);
    int i1 = __float2int_rn(v1 * sc);
    return (((unsigned long long)(unsigned)i1) << 32)
         + (unsigned long long)(long long)i0;
}

// ---------------------------------------------------------------------------
// setup: zero d_out (grid-stride) + pack W2 into bf16 B-frag order + pack W1
// into f16 k-pairs (r9-verified). Zero bits == u64 0 == accumulation identity.
// ---------------------------------------------------------------------------
__global__ void setup_kernel(const float* __restrict__ W2,
                             const float* __restrict__ W1,
                             unsigned short* __restrict__ wsB,
                             unsigned* __restrict__ w1p,
                             int4* __restrict__ out, int n16) {
    int gid = blockIdx.x * 256 + threadIdx.x;
    for (int i = gid; i < n16; i += gridDim.x * 256)
        out[i] = make_int4(0, 0, 0, 0);
    if (gid < 36864) {
        int j    = gid & 7;
        int lane = (gid >> 3) & 63;
        int ks   = (gid >> 9) & 1;
        int nt   = gid >> 10;
        int k = ks * 32 + (lane >> 4) * 8 + j;
        int n = nt * 16 + (lane & 15);
        wsB[gid] = f2bf(W2[k * 576 + n]);
    } else if (gid < 36864 + 512) {
        int idx = gid - 36864;
        int kk  = idx >> 6;
        int i   = idx & 63;
        __half lo = __float2half(W1[(2*kk)     * 64 + i]);
        __half hi = __float2half(W1[(2*kk + 1) * 64 + i]);
        w1p[idx] = (unsigned)__half_as_ushort(lo)
                 | ((unsigned)__half_as_ushort(hi) << 16);
    }
}

// ---------------------------------------------------------------------------
// finalize: in-place packed-u64 fxp -> 2x float. uint4 = two u64 sums.
// Exact decode: lo = (int)low32; hi = (int)high32 + (low32 >> 31).
// Single pointer type (no aliasing UB, r8/r9-validated pattern).
// ---------------------------------------------------------------------------
__global__ void finalize_kernel(uint4* p, int n16) {
    int i = blockIdx.x * blockDim.x + threadIdx.x;
    if (i < n16) {
        uint4 v = p[i];
        int lo0 = (int)v.x, hi0 = (int)v.y + (int)(v.x >> 31);
        int lo1 = (int)v.z, hi1 = (int)v.w + (int)(v.z >> 31);
        uint4 o;
        o.x = __float_as_uint((float)lo0 * FXP32_INV);
        o.y = __float_as_uint((float)hi0 * FXP32_INV);
        o.z = __float_as_uint((float)lo1 * FXP32_INV);
        o.w = __float_as_uint((float)hi1 * FXP32_INV);
        p[i] = o;
    }
}

// ---------------------------------------------------------------------------
// fused conv. v11 = v9 (fastest verified: dot2 h-path, 1-wave blocks,
// launch_bounds(64,2)) with the epilogue emitting PAIRED u64 atomics:
// 20 atomic instrs/lane instead of 40. Theory: 32M scattered dword atomics
// saturate L2 atomic pipes (~154-307 Gops/s => 104-208 us floor) and inflate
// latency for everything else; halving op count attacks that wall directly.
// ---------------------------------------------------------------------------
__global__ __launch_bounds__(64, 2) void conv_kernel(
    const float* __restrict__ pos,
    const float* __restrict__ f_in,
    const int*   __restrict__ esrc,
    const int*   __restrict__ edst,
    const unsigned* __restrict__ w1p,
    const unsigned short* __restrict__ wsB,
    unsigned long long* __restrict__ f_out_u)
{
    // 9216 B region, reused in phases (wave-local lgkmcnt only):
    //   ph1: h-stage 64x72 bf16 (stride 144 B)          = 9216 B
    //   ph2: x0t 16x64 f32 [0,4096) + dott 8x64 [4096,6144)
    //   ph3: x1t 24x64 f32 [0,6144)
    //   ph4: E1 out0+sh+dst, stride 20 f32              = 5120 B
    //   ph5: E2 out1-fused+dst, stride 28 f32           = 7168 B
    __shared__ __align__(16) char smem[9216];

    const int lane = threadIdx.x;
    const int e    = blockIdx.x * 64 + lane;
    char*  my  = smem;
    float* shf = (float*)smem;

    const int s = esrc[e];
    const int d = edst[e];

    // early B prefetch: chunks 0 and 1
    const bf16x8* wsBv = (const bf16x8*)wsB;
    bf16x8 bc0 = wsBv[lane],        bc1 = wsBv[64 + lane];
    bf16x8 bn0 = wsBv[128 + lane],  bn1 = wsBv[192 + lane];
    bf16x8 b20, b21;

    // --- geometry -----------------------------------------------------------
    float px = pos[3*d+0] - pos[3*s+0];
    float py = pos[3*d+1] - pos[3*s+1];
    float pz = pos[3*d+2] - pos[3*s+2];
    float r  = sqrtf(px*px + py*py + pz*pz + 1e-12f);
    float inv_r = __builtin_amdgcn_rcpf(r);
    float ux = px*inv_r, uy = py*inv_r, uz = pz*inv_r;
    const float SQ3 = 1.7320508075688772f;
    float shx = SQ3*ux, shy = SQ3*uy, shz = SQ3*uz;

    // --- x = f_in[src] ------------------------------------------------------
    float x0[16], x1[24], dot[8];
    {
        const float4* xg4 = reinterpret_cast<const float4*>(f_in + (size_t)s * 40);
        float xr[40];
        #pragma unroll
        for (int q8 = 0; q8 < 10; ++q8) {
            float4 v = xg4[q8];
            xr[4*q8+0] = v.x; xr[4*q8+1] = v.y; xr[4*q8+2] = v.z; xr[4*q8+3] = v.w;
        }
        #pragma unroll
        for (int i = 0; i < 16; ++i) x0[i] = xr[i];
        #pragma unroll
        for (int i = 0; i < 24; ++i) x1[i] = xr[16+i];
        #pragma unroll
        for (int u = 0; u < 8; ++u)
            dot[u] = x1[3*u+0]*ux + x1[3*u+1]*uy + x1[3*u+2]*uz;  // = inv_s3*(x1.sh1)
    }

    // --- radial embedding (dense, verified) ---------------------------------
    const float A = 1.14136f * 7.38905609893065f;   // 1.14136 * e^2
    const float inv_step = 17.0f / 5.0f;
    float emb[16];
    #pragma unroll
    for (int k = 0; k < 16; ++k) {
        float dd  = r * inv_step - (float)(k + 1);
        float d2v = dd * dd;
        float arg = -2.0f * __builtin_amdgcn_rcpf(1.0f - d2v);
        float val = A * __expf(arg);
        emb[k] = (d2v < 1.0f) ? val : 0.0f;
    }

    // --- h = silu(emb @ W1) via f16 dot2 (verified v7/v9) --------------------
    unsigned ep[8];
    #pragma unroll
    for (int kk = 0; kk < 8; ++kk) {
        __half lo = __float2half(emb[2*kk]);
        __half hi = __float2half(emb[2*kk+1]);
        ep[kk] = (unsigned)__half_as_ushort(lo)
               | ((unsigned)__half_as_ushort(hi) << 16);
    }
    float h[64];
    #pragma unroll
    for (int i = 0; i < 64; ++i) h[i] = 0.f;
    #pragma unroll
    for (int kk = 0; kk < 8; ++kk) {
        h16x2 ev = __builtin_bit_cast(h16x2, ep[kk]);
        const unsigned* wrow = w1p + kk * 64;
        #pragma unroll
        for (int i = 0; i < 64; ++i) {
            h16x2 wv = __builtin_bit_cast(h16x2, wrow[i]);
            h[i] = FDOT2(ev, wv, h[i]);
        }
    }
    #pragma unroll
    for (int i = 0; i < 64; ++i) {
        float z = h[i];
        h[i] = z * __builtin_amdgcn_rcpf(1.0f + __expf(-z));
    }

    // --- stage h -> LDS [edge][k] bf16, row stride 144 B -------------------
    {
        unsigned int hp[32];
        #pragma unroll
        for (int i = 0; i < 32; ++i)
            hp[i] = (unsigned)f2bf(h[2*i]) | ((unsigned)f2bf(h[2*i+1]) << 16);
        uint4* hrow = (uint4*)(my + lane * 144);
        #pragma unroll
        for (int g = 0; g < 8; ++g)
            hrow[g] = make_uint4(hp[4*g], hp[4*g+1], hp[4*g+2], hp[4*g+3]);
    }
    asm volatile("s_waitcnt lgkmcnt(0)" ::: "memory");

    // --- A fragments --------------------------------------------------------
    const int q   = lane >> 4;
    const int col = lane & 15;
    const int q4  = q * 4;
    const int ucol = col >> 3;     // u-parity for w01/w10 paths
    bf16x8 aF[4][2];
    #pragma unroll
    for (int mt = 0; mt < 4; ++mt)
        #pragma unroll
        for (int ks = 0; ks < 2; ++ks)
            aF[mt][ks] = *(const bf16x8*)(my + (mt*16 + col)*144 + q*16 + ks*64);
    asm volatile("s_waitcnt lgkmcnt(0)" ::: "memory");   // aF reads done before overwrite

    // --- stage x0t + dott (h region now dead) ------------------------------
    #pragma unroll
    for (int u = 0; u < 16; ++u) shf[u*64 + lane] = x0[u];
    #pragma unroll
    for (int u = 0; u < 8;  ++u) shf[1024 + u*64 + lane] = dot[u];
    asm volatile("s_waitcnt lgkmcnt(0)" ::: "memory");

    // --- distributed accumulators (C-layout: lane has edges 4q+r, col) ------
    f32x4 out0d[4], t01d[4], o1bd[4][3];
    #pragma unroll
    for (int m = 0; m < 4; ++m) {
        out0d[m] = (f32x4){0.f,0.f,0.f,0.f};
        t01d[m]  = (f32x4){0.f,0.f,0.f,0.f};
        #pragma unroll
        for (int k = 0; k < 3; ++k) o1bd[m][k] = (f32x4){0.f,0.f,0.f,0.f};
    }

#define MFMA8() \
    f32x4 wr0 = {0.f,0.f,0.f,0.f}, wr1 = {0.f,0.f,0.f,0.f}; \
    f32x4 wr2 = {0.f,0.f,0.f,0.f}, wr3 = {0.f,0.f,0.f,0.f}; \
    wr0 = __builtin_amdgcn_mfma_f32_16x16x32_bf16(aF[0][0], bc0, wr0, 0,0,0); \
    wr1 = __builtin_amdgcn_mfma_f32_16x16x32_bf16(aF[1][0], bc0, wr1, 0,0,0); \
    wr2 = __builtin_amdgcn_mfma_f32_16x16x32_bf16(aF[2][0], bc0, wr2, 0,0,0); \
    wr3 = __builtin_amdgcn_mfma_f32_16x16x32_bf16(aF[3][0], bc0, wr3, 0,0,0); \
    wr0 = __builtin_amdgcn_mfma_f32_16x16x32_bf16(aF[0][1], bc1, wr0, 0,0,0); \
    wr1 = __builtin_amdgcn_mfma_f32_16x16x32_bf16(aF[1][1], bc1, wr1, 0,0,0); \
    wr2 = __builtin_amdgcn_mfma_f32_16x16x32_bf16(aF[2][1], bc1, wr2, 0,0,0); \
    wr3 = __builtin_amdgcn_mfma_f32_16x16x32_bf16(aF[3][1], bc1, wr3, 0,0,0);

#define PRE(NT2) { b20 = wsBv[(NT2)*128 + lane]; b21 = wsBv[(NT2)*128 + 64 + lane]; }
#define ROT()    { bc0 = bn0; bc1 = bn1; bn0 = b20; bn1 = b21; }

// broadcast-read 4 x f32x4 from xT row BASEW and fma into ACC[0..3]
#define CONS4(ACC, BASEW) { \
    const float* xb_ = shf + (BASEW) + q4; \
    ACC[0] = fma4(wr0, *(const f32x4*)(xb_ +  0), ACC[0]); \
    ACC[1] = fma4(wr1, *(const f32x4*)(xb_ + 16), ACC[1]); \
    ACC[2] = fma4(wr2, *(const f32x4*)(xb_ + 32), ACC[2]); \
    ACC[3] = fma4(wr3, *(const f32x4*)(xb_ + 48), ACC[3]); }

    // --- w00: chunks 0..15 (cols u*16+col) ---------------------------------
    #pragma unroll
    for (int u = 0; u < 16; ++u) {
        PRE(u + 2);                         // 2..17
        MFMA8();
        CONS4(out0d, u * 64);
        ROT();
    }
    // --- w01: chunks 16..23 (u = 2t+ucol, v = col&7) -----------------------
    #pragma unroll
    for (int t = 0; t < 8; ++t) {
        PRE(t < 6 ? 18 + t : 28 + (t - 6)); // 18..23, 28, 29
        MFMA8();
        CONS4(t01d, (2*t + ucol) * 64);
        ROT();
    }
    // resolve u-parity partials: lanes col and col^8 hold complementary sums
    #pragma unroll
    for (int m = 0; m < 4; ++m)
        #pragma unroll
        for (int rr = 0; rr < 4; ++rr)
            t01d[m][rr] += __shfl_xor(t01d[m][rr], 8);

    // --- w11: chunks 28..35 (cols u*16+col, scalar = dot) ------------------
    #pragma unroll
    for (int u = 0; u < 8; ++u) {
        PRE(u < 6 ? 30 + u : 24 + (u - 6)); // 30..35, 24, 25
        MFMA8();
        CONS4(out0d, 1024 + u * 64);
        ROT();
    }

    // --- restage x1t (x0t/dott dead); drain reads first --------------------
    asm volatile("s_waitcnt lgkmcnt(0)" ::: "memory");
    #pragma unroll
    for (int u = 0; u < 8; ++u)
        #pragma unroll
        for (int k = 0; k < 3; ++k)
            shf[(u*3 + k)*64 + lane] = x1[3*u + k];
    asm volatile("s_waitcnt lgkmcnt(0)" ::: "memory");

    // --- w10: chunks 24..27 (u = 2t+ucol, v = col&7, vector over k) --------
    #pragma unroll
    for (int t = 0; t < 4; ++t) {
        if (t < 2) PRE(26 + t);             // 26, 27
        MFMA8();
        const int ub = (2*t + ucol) * 192 + q4;
#define W10_MT(MT, WR) { \
        f32x4 xv0 = *(const f32x4*)(shf + ub +   0 + 16*(MT)); \
        f32x4 xv1 = *(const f32x4*)(shf + ub +  64 + 16*(MT)); \
        f32x4 xv2 = *(const f32x4*)(shf + ub + 128 + 16*(MT)); \
        o1bd[MT][0] = fma4(WR, xv0, o1bd[MT][0]); \
        o1bd[MT][1] = fma4(WR, xv1, o1bd[MT][1]); \
        o1bd[MT][2] = fma4(WR, xv2, o1bd[MT][2]); }
        W10_MT(0, wr0) W10_MT(1, wr1) W10_MT(2, wr2) W10_MT(3, wr3)
#undef W10_MT
        ROT();
    }
#undef CONS4
#undef PRE
#undef ROT
#undef MFMA8
    // resolve o1bd u-parity partials
    #pragma unroll
    for (int m = 0; m < 4; ++m)
        #pragma unroll
        for (int k = 0; k < 3; ++k)
            #pragma unroll
            for (int rr = 0; rr < 4; ++rr)
                o1bd[m][k][rr] += __shfl_xor(o1bd[m][k][rr], 8);

    // --- epilogue ----------------------------------------------------------
    const float FXP_S = (1.0f / (32.0f * 4.898979485566356f)) * FXP32_SCALE;

    // E1: out0 (v=col) + sh + dst, stride 20 words; drain w10 reads first
    asm volatile("s_waitcnt lgkmcnt(0)" ::: "memory");
    #pragma unroll
    for (int m = 0; m < 4; ++m)
        #pragma unroll
        for (int rr = 0; rr < 4; ++rr)
            shf[(16*m + 4*q + rr) * 20 + col] = out0d[m][rr];
    shf[lane*20 + 16] = shx;
    shf[lane*20 + 17] = shy;
    shf[lane*20 + 18] = shz;
    ((int*)shf)[lane*20 + 19] = d;
    asm volatile("s_waitcnt lgkmcnt(0)" ::: "memory");

    // 8 paired u64 atomics cover cols 0..15 of all 64 edges (512 pairs)
    #pragma unroll 4
    for (int it = 0; it < 8; ++it) {
        int p  = it * 64 + lane;         // 0..511
        int ee = p >> 3;
        int cp = p & 7;                  // pair -> cols 2cp, 2cp+1
        float v0 = shf[ee*20 + 2*cp];
        float v1 = shf[ee*20 + 2*cp + 1];
        int dd  = ((int*)shf)[ee*20 + 19];
        atomicAdd(f_out_u + (size_t)dd*20 + cp, pack_pair(v0, v1, FXP_S));
    }

    // E2: fused out1 = t01[v]*sh[k] + o1b[v][k], 24 words + dst, stride 28
    float shr[4][4][3];
    #pragma unroll
    for (int m = 0; m < 4; ++m)
        #pragma unroll
        for (int rr = 0; rr < 4; ++rr) {
            int eb = (16*m + 4*q + rr) * 20 + 16;
            shr[m][rr][0] = shf[eb + 0];
            shr[m][rr][1] = shf[eb + 1];
            shr[m][rr][2] = shf[eb + 2];
        }
    asm volatile("s_waitcnt lgkmcnt(0)" ::: "memory");   // shr reads done before overwrite
    if (col < 8) {
        #pragma unroll
        for (int m = 0; m < 4; ++m)
            #pragma unroll
            for (int rr = 0; rr < 4; ++rr)
                #pragma unroll
                for (int k = 0; k < 3; ++k) {
                    float fv = fmaf(t01d[m][rr], shr[m][rr][k], o1bd[m][k][rr]);
                    shf[(16*m + 4*q + rr) * 28 + 3*col + k] = fv;
                }
    }
    ((int*)shf)[lane*28 + 27] = d;
    asm volatile("s_waitcnt lgkmcnt(0)" ::: "memory");

    // 12 paired u64 atomics cover cols 16..39 of all 64 edges (768 pairs)
    #pragma unroll 4
    for (int it = 0; it < 12; ++it) {
        int p  = it * 64 + lane;         // 0..767
        int ee = (p * 21846) >> 18;      // p / 12, exact for p < 768
        int jp = p - ee * 12;            // pair -> cols 16+2jp, 17+2jp
        float v0 = shf[ee*28 + 2*jp];
        float v1 = shf[ee*28 + 2*jp + 1];
        int dd  = ((int*)shf)[ee*28 + 27];
        atomicAdd(f_out_u + (size_t)dd*20 + 8 + jp, pack_pair(v0, v1, FXP_S));
    }
}

extern "C" void kernel_launch(void* const* d_in, const int* in_sizes, int n_in,
                              void* d_out, int out_size, void* d_ws, size_t ws_size,
                              hipStream_t stream) {
    const float* pos  = (const float*)d_in[0];
    const float* f_in = (const float*)d_in[1];
    const int*   esrc = (const int*)  d_in[2];
    const int*   edst = (const int*)  d_in[3];
    const float* W1   = (const float*)d_in[4];
    const float* W2   = (const float*)d_in[5];
    float* out = (float*)d_out;

    unsigned short* wsB = (unsigned short*)d_ws;
    unsigned*       w1p = (unsigned*)((char*)d_ws + WSB_BYTES);

    const int nOut = N_NODES * 40;            // 2,000,000 floats
    const int n16  = nOut / 4;                // 500,000 uint4 = 1M u64 slots

    // setup: zero d_out + pack W2/W1 (one launch)
    setup_kernel<<<256, 256, 0, stream>>>(W2, W1, wsB, w1p, (int4*)out, n16);

    // conv: 1-wave blocks, paired-u64 fxp atomics into d_out
    conv_kernel<<<N_EDGES / 64, 64, 0, stream>>>(
        pos, f_in, esrc, edst, w1p, wsB, (unsigned long long*)out);

    // finalize: in-place packed-u64 -> 2x float (single pointer, exact decode)
    finalize_kernel<<<(n16 + 255) / 256, 256, 0, stream>>>((uint4*)out, n16);
}